// Round 1
// baseline (7631.773 us; speedup 1.0000x reference)
//
#include <hip/hip_runtime.h>
#include <stdint.h>

// UniLSTM: B=64, T=512, E=1024, H=1024.
// Phase 0: f32->f16 converts (embeddings, W_ih, W_hh) + bias sum.
// Phase 1: x_proj[B*T,4096] = x @ W_ih^T + bsum  (f16 MFMA GEMM, f16 output, fp32 accum)
// Phase 2: persistent recurrence: 256 WGs = 4 batch-groups x 64 unit-slices.
//          W_hh fragments VGPR-resident; h broadcast via LLC with agent-scope atomics.

typedef _Float16 half8 __attribute__((ext_vector_type(8)));
typedef _Float16 half4_ __attribute__((ext_vector_type(4)));
typedef float f32x4 __attribute__((ext_vector_type(4)));

#define T_SEQ 512

// ---------------- converts ----------------
__global__ void k_f32_to_f16(const float* __restrict__ s, _Float16* __restrict__ d, int n4) {
  int i = blockIdx.x * blockDim.x + threadIdx.x;
  if (i >= n4) return;
  f32x4 v = ((const f32x4*)s)[i];
  half4_ h;
  h.x = (_Float16)v.x; h.y = (_Float16)v.y; h.z = (_Float16)v.z; h.w = (_Float16)v.w;
  ((half4_*)d)[i] = h;
}

__global__ void k_bias_sum(const float* __restrict__ a, const float* __restrict__ b,
                           float* __restrict__ o) {
  int i = blockIdx.x * blockDim.x + threadIdx.x;
  if (i < 4096) o[i] = a[i] + b[i];
}

// ---------------- phase 1: input projection GEMM ----------------
// C[M=32768, N=4096] = X[M,1024] @ W[N,1024]^T + bsum[N]   (both K-major, m97 "bt" form)
__global__ __launch_bounds__(256, 2) void k_gemm_xproj(
    const _Float16* __restrict__ X, const _Float16* __restrict__ W,
    const float* __restrict__ bsum, _Float16* __restrict__ C) {
  __shared__ _Float16 As[128 * 64];  // 16 KB, rows of 64 f16 (128B), XOR-swizzled content
  __shared__ _Float16 Bs[128 * 64];
  const int bid = blockIdx.x;
  const int ntile = bid & 31, mtile = bid >> 5;
  const int tid = threadIdx.x;
  const int wave = tid >> 6, lane = tid & 63;
  const int wr = wave >> 1, wc = wave & 1;
  const int R0 = lane >> 3, cg = lane & 7;

  f32x4 acc[4][4];
#pragma unroll
  for (int m = 0; m < 4; m++)
#pragma unroll
    for (int n = 0; n < 4; n++) acc[m][n] = (f32x4){0.f, 0.f, 0.f, 0.f};

  for (int k0 = 0; k0 < 1024; k0 += 64) {
    // stage 16KB A + 16KB B: 4+4 global_load_lds(16B) per wave; LDS linear,
    // global source pre-swizzled (rule #21): LDS row rr holds k-group (cg ^ (rr&7))
#pragma unroll
    for (int i = 0; i < 4; i++) {
      const int rr = (wave * 4 + i) * 8 + R0;  // 0..127
      const _Float16* ga = X + (size_t)(mtile * 128 + rr) * 1024 + k0 + ((cg ^ (rr & 7)) * 8);
      const _Float16* gb = W + (size_t)(ntile * 128 + rr) * 1024 + k0 + ((cg ^ (rr & 7)) * 8);
      __builtin_amdgcn_global_load_lds(
          (const __attribute__((address_space(1))) void*)ga,
          (__attribute__((address_space(3))) void*)((char*)As + (wave * 4 + i) * 1024), 16, 0, 0);
      __builtin_amdgcn_global_load_lds(
          (const __attribute__((address_space(1))) void*)gb,
          (__attribute__((address_space(3))) void*)((char*)Bs + (wave * 4 + i) * 1024), 16, 0, 0);
    }
    asm volatile("s_waitcnt vmcnt(0)" ::: "memory");
    __syncthreads();
#pragma unroll
    for (int kk = 0; kk < 2; kk++) {
      half8 af[4], bf[4];
#pragma unroll
      for (int m = 0; m < 4; m++) {
        int r = wr * 64 + m * 16 + (lane & 15);
        af[m] = *(const half8*)((const char*)As + r * 128 +
                                (((kk * 4 + (lane >> 4)) ^ (r & 7)) << 4));
      }
#pragma unroll
      for (int n = 0; n < 4; n++) {
        int r = wc * 64 + n * 16 + (lane & 15);
        bf[n] = *(const half8*)((const char*)Bs + r * 128 +
                                (((kk * 4 + (lane >> 4)) ^ (r & 7)) << 4));
      }
#pragma unroll
      for (int m = 0; m < 4; m++)
#pragma unroll
        for (int n = 0; n < 4; n++)
          acc[m][n] = __builtin_amdgcn_mfma_f32_16x16x32_f16(af[m], bf[n], acc[m][n], 0, 0, 0);
    }
    __syncthreads();
  }
  // epilogue: C/D layout col=lane&15, row=(lane>>4)*4+q  [m89]
#pragma unroll
  for (int n = 0; n < 4; n++) {
    int col = ntile * 128 + wc * 64 + n * 16 + (lane & 15);
    float bs = bsum[col];
#pragma unroll
    for (int m = 0; m < 4; m++)
#pragma unroll
      for (int q = 0; q < 4; q++) {
        int row = mtile * 128 + wr * 64 + m * 16 + (lane >> 4) * 4 + q;
        C[(size_t)row * 4096 + col] = (_Float16)(acc[m][n][q] + bs);
      }
  }
}

// ---------------- phase 2: recurrence ----------------
// 256 WGs x 256 thr. WG = (group g = wg>>6 [16 batch rows], slice s = wg&63 [16 hidden units]).
// wave n (0..3) = gate type n (i,f,g,o): rows 1024*n + 16*s .. +16 of W_hh.
// Per step: gates[16b x 64g] = h_lds[16x1024] @ Wfrag + x_proj; elementwise -> h,c;
// h written agent-scope to LLC; per-group 64-WG barrier on cnt[g][t].
__global__ __launch_bounds__(256, 1) void k_lstm_rec(
    const _Float16* __restrict__ Whh,    // [4096][1024] f16
    const _Float16* __restrict__ xproj,  // [B*T][4096] f16
    const int* __restrict__ seqlen,      // [64]
    _Float16* __restrict__ hbuf,         // [2][64][1024] f16 ping-pong
    unsigned* __restrict__ cnt,          // [4][512] zeroed per launch
    float* __restrict__ out) {           // [64][1024] f32
  __shared__ _Float16 h_lds[16 * 1024];  // 32 KB, XOR-swizzled
  __shared__ float gates[16 * 64];       // 4 KB

  const int wg = blockIdx.x;
  const int g = wg >> 6, s = wg & 63;
  const int tid = threadIdx.x;
  const int wave = tid >> 6, lane = tid & 63;

  for (int i = tid; i < 4096; i += 256) ((uint64_t*)h_lds)[i] = 0ull;  // h_0 = 0

  // W_hh B-fragments, VGPR-resident for the whole kernel.
  // B-frag: lane l -> col n = l&15 (unit), k = kk*32 + (l>>4)*8 + j
  half8 wfrag[32];
  {
    const _Float16* wrow =
        Whh + (size_t)(1024 * wave + 16 * s + (lane & 15)) * 1024 + (lane >> 4) * 8;
#pragma unroll
    for (int kk = 0; kk < 32; kk++) wfrag[kk] = *(const half8*)(wrow + kk * 32);
  }

  int Lg = 1;
  for (int b = 0; b < 16; b++) {
    int L = seqlen[g * 16 + b];
    Lg = L > Lg ? L : Lg;
  }
  const int be = tid >> 4, ue = tid & 15;  // elementwise cell (batch-local, unit-local)
  const int mylen = seqlen[g * 16 + be];
  float c_state = 0.f;

  __syncthreads();

  for (int t = 0; t < Lg; t++) {
    // x_proj prefetch for this step (no dependency on h) — overlaps the spin
    float xp[4];
#pragma unroll
    for (int q = 0; q < 4; q++) {
      int bl = (lane >> 4) * 4 + q;
      size_t row = (size_t)(g * 16 + bl) * T_SEQ + t;
      xp[q] = (float)xproj[row * 4096 + 1024 * wave + 16 * s + (lane & 15)];
    }
    if (t > 0) {
      if (tid == 0) {
        while (__hip_atomic_load(&cnt[g * 512 + (t - 1)], __ATOMIC_RELAXED,
                                 __HIP_MEMORY_SCOPE_AGENT) < 64u) {}
      }
      __syncthreads();
      __builtin_amdgcn_fence(__ATOMIC_ACQUIRE, "agent");  // invalidate stale L1/L2
      // stage h_t [16][1024] f16 -> LDS, linear dest + pre-swizzled global source
      const _Float16* hsrc = hbuf + ((size_t)(t & 1)) * 65536 + (size_t)(g * 16) * 1024;
#pragma unroll
      for (int i = 0; i < 8; i++) {
        int L = (wave * 8 + i) * 1024 + lane * 16;
        int b = L >> 11;
        int K4 = (L >> 4) & 127;
        const _Float16* gp = hsrc + b * 1024 + ((K4 ^ (b & 7)) * 8);
        __builtin_amdgcn_global_load_lds(
            (const __attribute__((address_space(1))) void*)gp,
            (__attribute__((address_space(3))) void*)((char*)h_lds + (wave * 8 + i) * 1024), 16,
            0, 0);
      }
      asm volatile("s_waitcnt vmcnt(0)" ::: "memory");
    }
    __syncthreads();

    // gates tile: M=16 batch x N=16 units, K=1024 -> 32 MFMAs
    f32x4 acc = (f32x4){0.f, 0.f, 0.f, 0.f};
    const int bA = lane & 15;
    const int baseA = bA * 2048;
#pragma unroll
    for (int kk = 0; kk < 32; kk++) {
      half8 af = *(const half8*)((const char*)h_lds + baseA +
                                 (((kk * 4 + (lane >> 4)) ^ (bA & 7)) << 4));
      acc = __builtin_amdgcn_mfma_f32_16x16x32_f16(af, wfrag[kk], acc, 0, 0, 0);
    }
#pragma unroll
    for (int q = 0; q < 4; q++) {
      int bm = (lane >> 4) * 4 + q;
      gates[bm * 64 + wave * 16 + (lane & 15)] = acc[q] + xp[q];
    }
    __syncthreads();

    // elementwise: thread owns cell (be, ue); c in fp32 register across all steps
    float iv = gates[be * 64 + ue];
    float fv = gates[be * 64 + 16 + ue];
    float gv = gates[be * 64 + 32 + ue];
    float ov = gates[be * 64 + 48 + ue];
    iv = 1.f / (1.f + __expf(-iv));
    fv = 1.f / (1.f + __expf(-fv));
    gv = 1.f - 2.f / (1.f + __expf(2.f * gv));
    ov = 1.f / (1.f + __expf(-ov));
    c_state = fv * c_state + iv * gv;
    float tc = 1.f - 2.f / (1.f + __expf(2.f * c_state));
    float hv = ov * tc;
    if (t + 1 == mylen) out[(size_t)(g * 16 + be) * 1024 + s * 16 + ue] = hv;

    _Float16 hf = (_Float16)hv;
    unsigned short hb;
    __builtin_memcpy(&hb, &hf, 2);
    // agent-scope store -> LLC (bypass non-coherent local L2)
    __hip_atomic_store((unsigned short*)hbuf + ((size_t)((t + 1) & 1)) * 65536 +
                           (size_t)(g * 16 + be) * 1024 + s * 16 + ue,
                       hb, __ATOMIC_RELAXED, __HIP_MEMORY_SCOPE_AGENT);
    __syncthreads();  // drains vmcnt for all waves before the arrive
    if (tid == 0)
      __hip_atomic_fetch_add(&cnt[g * 512 + t], 1u, __ATOMIC_RELEASE, __HIP_MEMORY_SCOPE_AGENT);
  }
}

// ---------------- launch ----------------
extern "C" void kernel_launch(void* const* d_in, const int* in_sizes, int n_in, void* d_out,
                              int out_size, void* d_ws, size_t ws_size, hipStream_t stream) {
  const float* emb = (const float*)d_in[0];   // [64,512,1024]
  const int* slen = (const int*)d_in[1];      // [64]
  const float* Wih = (const float*)d_in[2];   // [4096,1024]
  const float* Whh = (const float*)d_in[3];   // [4096,1024]
  const float* bih = (const float*)d_in[4];   // [4096]
  const float* bhh = (const float*)d_in[5];   // [4096]
  float* out = (float*)d_out;

  char* ws = (char*)d_ws;  // needs ~336.3 MB
  _Float16* xproj = (_Float16*)(ws + 0);          // 268,435,456 B
  _Float16* xf = (_Float16*)(ws + 268435456);     //  67,108,864 B
  _Float16* wihf = (_Float16*)(ws + 335544320);   //   8,388,608 B
  _Float16* whhf = (_Float16*)(ws + 343932928);   //   8,388,608 B
  float* bsum = (float*)(ws + 352321536);         //      16,384 B
  _Float16* hbuf = (_Float16*)(ws + 352337920);   //     262,144 B
  unsigned* cnt = (unsigned*)(ws + 352600064);    //       8,192 B

  hipMemsetAsync(cnt, 0, 8192, stream);
  k_f32_to_f16<<<(8388608 + 255) / 256, 256, 0, stream>>>(emb, xf, 8388608);
  k_f32_to_f16<<<(1048576 + 255) / 256, 256, 0, stream>>>(Wih, wihf, 1048576);
  k_f32_to_f16<<<(1048576 + 255) / 256, 256, 0, stream>>>(Whh, whhf, 1048576);
  k_bias_sum<<<16, 256, 0, stream>>>(bih, bhh, bsum);
  k_gemm_xproj<<<8192, 256, 0, stream>>>(xf, wihf, bsum, xproj);
  k_lstm_rec<<<256, 256, 0, stream>>>(whhf, xproj, slen, hbuf, cnt, out);
}

// Round 2
// 2073.226 us; speedup vs baseline: 3.6811x; 3.6811x over previous
//
#include <hip/hip_runtime.h>
#include <stdint.h>

// UniLSTM: B=64, T=512, E=1024, H=1024.
// Phase 0: f32->f16 converts (embeddings, W_ih, W_hh) + bias sum.
// Phase 1: x_proj[B*T,4096] = x @ W_ih^T + bsum  (f16 MFMA GEMM, f16 output, fp32 accum)
// Phase 2: persistent recurrence: 256 WGs = 4 batch-groups x 64 unit-slices.
//          W_hh fragments register-resident; h exchanged through LLC with
//          fence-free dataflow sync (per-WG flags + L2-bypass loads). No
//          buffer_wbl2 / buffer_inv anywhere in the step loop (R1 lesson).

typedef _Float16 half8 __attribute__((ext_vector_type(8)));
typedef _Float16 half4_ __attribute__((ext_vector_type(4)));
typedef float f32x4 __attribute__((ext_vector_type(4)));
typedef unsigned int u32x4 __attribute__((ext_vector_type(4)));

#define T_SEQ 512

// ---------------- converts ----------------
__global__ void k_f32_to_f16(const float* __restrict__ s, _Float16* __restrict__ d, int n4) {
  int i = blockIdx.x * blockDim.x + threadIdx.x;
  if (i >= n4) return;
  f32x4 v = ((const f32x4*)s)[i];
  half4_ h;
  h.x = (_Float16)v.x; h.y = (_Float16)v.y; h.z = (_Float16)v.z; h.w = (_Float16)v.w;
  ((half4_*)d)[i] = h;
}

__global__ void k_bias_sum(const float* __restrict__ a, const float* __restrict__ b,
                           float* __restrict__ o) {
  int i = blockIdx.x * blockDim.x + threadIdx.x;
  if (i < 4096) o[i] = a[i] + b[i];
}

// ---------------- phase 1: input projection GEMM ----------------
// C[M=32768, N=4096] = X[M,1024] @ W[N,1024]^T + bsum[N]
__global__ __launch_bounds__(256, 2) void k_gemm_xproj(
    const _Float16* __restrict__ X, const _Float16* __restrict__ W,
    const float* __restrict__ bsum, _Float16* __restrict__ C) {
  __shared__ _Float16 As[128 * 64];  // 16 KB, rows of 64 f16 (128B), XOR-swizzled content
  __shared__ _Float16 Bs[128 * 64];
  const int bid = blockIdx.x;
  const int ntile = bid & 31, mtile = bid >> 5;
  const int tid = threadIdx.x;
  const int wave = tid >> 6, lane = tid & 63;
  const int wr = wave >> 1, wc = wave & 1;
  const int R0 = lane >> 3, cg = lane & 7;

  f32x4 acc[4][4];
#pragma unroll
  for (int m = 0; m < 4; m++)
#pragma unroll
    for (int n = 0; n < 4; n++) acc[m][n] = (f32x4){0.f, 0.f, 0.f, 0.f};

  for (int k0 = 0; k0 < 1024; k0 += 64) {
#pragma unroll
    for (int i = 0; i < 4; i++) {
      const int rr = (wave * 4 + i) * 8 + R0;  // 0..127
      const _Float16* ga = X + (size_t)(mtile * 128 + rr) * 1024 + k0 + ((cg ^ (rr & 7)) * 8);
      const _Float16* gb = W + (size_t)(ntile * 128 + rr) * 1024 + k0 + ((cg ^ (rr & 7)) * 8);
      __builtin_amdgcn_global_load_lds(
          (const __attribute__((address_space(1))) void*)ga,
          (__attribute__((address_space(3))) void*)((char*)As + (wave * 4 + i) * 1024), 16, 0, 0);
      __builtin_amdgcn_global_load_lds(
          (const __attribute__((address_space(1))) void*)gb,
          (__attribute__((address_space(3))) void*)((char*)Bs + (wave * 4 + i) * 1024), 16, 0, 0);
    }
    asm volatile("s_waitcnt vmcnt(0)" ::: "memory");
    __syncthreads();
#pragma unroll
    for (int kk = 0; kk < 2; kk++) {
      half8 af[4], bf[4];
#pragma unroll
      for (int m = 0; m < 4; m++) {
        int r = wr * 64 + m * 16 + (lane & 15);
        af[m] = *(const half8*)((const char*)As + r * 128 +
                                (((kk * 4 + (lane >> 4)) ^ (r & 7)) << 4));
      }
#pragma unroll
      for (int n = 0; n < 4; n++) {
        int r = wc * 64 + n * 16 + (lane & 15);
        bf[n] = *(const half8*)((const char*)Bs + r * 128 +
                                (((kk * 4 + (lane >> 4)) ^ (r & 7)) << 4));
      }
#pragma unroll
      for (int m = 0; m < 4; m++)
#pragma unroll
        for (int n = 0; n < 4; n++)
          acc[m][n] = __builtin_amdgcn_mfma_f32_16x16x32_f16(af[m], bf[n], acc[m][n], 0, 0, 0);
    }
    __syncthreads();
  }
#pragma unroll
  for (int n = 0; n < 4; n++) {
    int col = ntile * 128 + wc * 64 + n * 16 + (lane & 15);
    float bs = bsum[col];
#pragma unroll
    for (int m = 0; m < 4; m++)
#pragma unroll
      for (int q = 0; q < 4; q++) {
        int row = mtile * 128 + wr * 64 + m * 16 + (lane >> 4) * 4 + q;
        C[(size_t)row * 4096 + col] = (_Float16)(acc[m][n][q] + bs);
      }
  }
}

// ---------------- phase 2: recurrence ----------------
// 256 WGs x 256 thr. WG = (group g = wg>>6 [16 batch rows], slice s = wg&63 [16 hidden units]).
// wave n (0..3) = gate type n (i,f,g,o): rows 1024*n + 16*s .. +16 of W_hh.
// Fence-free sync: producers drain h stores via __syncthreads (vmcnt(0) before
// s_barrier), then store flags[g][t][s]=1 relaxed/agent. Consumers ballot-poll
// the 64 flags, then gather h with sc0+sc1 (L2-bypass) dwordx4 loads.
__global__ __launch_bounds__(256, 1) void k_lstm_rec(
    const _Float16* __restrict__ Whh,    // [4096][1024] f16
    const _Float16* __restrict__ xproj,  // [B*T][4096] f16
    const int* __restrict__ seqlen,      // [64]
    _Float16* __restrict__ hbuf,         // [2][64][1024] f16 ping-pong
    unsigned* __restrict__ flags,        // [4][512][64] zeroed per launch
    float* __restrict__ out) {           // [64][1024] f32
  __shared__ _Float16 h_lds[16 * 1024];  // 32 KB, XOR-swizzled 16B chunks
  __shared__ float gates[16 * 64];       // 4 KB

  const int wg = blockIdx.x;
  const int g = wg >> 6, s = wg & 63;
  const int tid = threadIdx.x;
  const int wave = tid >> 6, lane = tid & 63;

  for (int i = tid; i < 4096; i += 256) ((uint64_t*)h_lds)[i] = 0ull;  // h_0 = 0

  // W_hh B-fragments, register-resident for the whole kernel.
  // B-frag: lane l -> col n = l&15 (unit), k = kk*32 + (l>>4)*8 + j  (validated R1)
  half8 wfrag[32];
  {
    const _Float16* wrow =
        Whh + (size_t)(1024 * wave + 16 * s + (lane & 15)) * 1024 + (lane >> 4) * 8;
#pragma unroll
    for (int kk = 0; kk < 32; kk++) wfrag[kk] = *(const half8*)(wrow + kk * 32);
  }

  int Lg = 1;
  for (int b = 0; b < 16; b++) {
    int L = seqlen[g * 16 + b];
    Lg = L > Lg ? L : Lg;
  }
  const int be = tid >> 4, ue = tid & 15;  // elementwise cell (batch-local, unit-local)
  const int mylen = seqlen[g * 16 + be];
  float c_state = 0.f;

  const int bA = lane & 15;          // A-frag batch row
  const int rowbase = bA * 2048;     // byte base of that row in h_lds
  const int xorm = (bA & 7) << 4;    // XOR swizzle mask (bytes)

  __syncthreads();

  for (int t = 0; t < Lg; t++) {
    // x_proj prefetch for this step (independent of h) — overlaps the spin
    float xp[4];
#pragma unroll
    for (int q = 0; q < 4; q++) {
      int bl = (lane >> 4) * 4 + q;
      size_t row = (size_t)(g * 16 + bl) * T_SEQ + t;
      xp[q] = (float)xproj[row * 4096 + 1024 * wave + 16 * s + (lane & 15)];
    }
    if (t > 0) {
      // ---- spin: all 4 waves poll the 64 per-WG flags for step t-1 ----
      const unsigned* fl = flags + (((size_t)g * 512 + (t - 1)) << 6);
      for (;;) {
        unsigned v = __hip_atomic_load(&fl[lane], __ATOMIC_RELAXED, __HIP_MEMORY_SCOPE_AGENT);
        if (__ballot(v != 0u) == ~0ull) break;
      }
      // ---- gather h_t [16][1024] f16 from LLC, L2-bypass, -> swizzled LDS ----
      const _Float16* hsrc = hbuf + ((size_t)(t & 1)) * 65536 + (size_t)(g * 16) * 1024;
      u32x4 hv[8];
#pragma unroll
      for (int i = 0; i < 8; i++) {
        int ch = tid + (i << 8);  // 16B chunk id, 0..2047
        asm volatile("global_load_dwordx4 %0, %1, off sc0 sc1"
                     : "=v"(hv[i]) : "v"(hsrc + ch * 8) : "memory");
      }
      asm volatile("s_waitcnt vmcnt(0)" ::: "memory");
#pragma unroll
      for (int i = 0; i < 8; i++) {
        int ch = tid + (i << 8);
        int b = ch >> 7, j = ch & 127;
        *(u32x4*)((char*)h_lds + b * 2048 + ((j ^ (b & 7)) << 4)) = hv[i];
      }
    }
    __syncthreads();  // (A) h_lds ready

    // gates tile: M=16 batch x N=16 units, K=1024 -> 32 MFMAs, 2 accumulators
    f32x4 acc0 = (f32x4){0.f, 0.f, 0.f, 0.f};
    f32x4 acc1 = (f32x4){0.f, 0.f, 0.f, 0.f};
#pragma unroll
    for (int kk = 0; kk < 32; kk += 2) {
      half8 a0 = *(const half8*)((const char*)h_lds + rowbase +
                                 ((((kk + 0) * 4 + (lane >> 4)) << 4) ^ xorm));
      half8 a1 = *(const half8*)((const char*)h_lds + rowbase +
                                 ((((kk + 1) * 4 + (lane >> 4)) << 4) ^ xorm));
      acc0 = __builtin_amdgcn_mfma_f32_16x16x32_f16(a0, wfrag[kk], acc0, 0, 0, 0);
      acc1 = __builtin_amdgcn_mfma_f32_16x16x32_f16(a1, wfrag[kk + 1], acc1, 0, 0, 0);
    }
#pragma unroll
    for (int q = 0; q < 4; q++) {
      int bm = (lane >> 4) * 4 + q;
      gates[bm * 64 + wave * 16 + (lane & 15)] = (acc0[q] + acc1[q]) + xp[q];
    }
    __syncthreads();  // (B) gates ready

    // elementwise: thread owns cell (be, ue); c stays fp32 in-register
    float iv = gates[be * 64 + ue];
    float fv = gates[be * 64 + 16 + ue];
    float gv = gates[be * 64 + 32 + ue];
    float ov = gates[be * 64 + 48 + ue];
    iv = 1.f / (1.f + __expf(-iv));
    fv = 1.f / (1.f + __expf(-fv));
    gv = 1.f - 2.f / (1.f + __expf(2.f * gv));
    ov = 1.f / (1.f + __expf(-ov));
    c_state = fv * c_state + iv * gv;
    float tc = 1.f - 2.f / (1.f + __expf(2.f * c_state));
    float hv = ov * tc;
    if (t + 1 == mylen) out[(size_t)(g * 16 + be) * 1024 + s * 16 + ue] = hv;

    _Float16 hf = (_Float16)hv;
    unsigned short hb;
    __builtin_memcpy(&hb, &hf, 2);
    // L2-bypassing store -> LLC (single coherence point)
    __hip_atomic_store((unsigned short*)hbuf + ((size_t)((t + 1) & 1)) * 65536 +
                           (size_t)(g * 16 + be) * 1024 + s * 16 + ue,
                       hb, __ATOMIC_RELAXED, __HIP_MEMORY_SCOPE_AGENT);
    __syncthreads();  // (C) vmcnt(0) drain before flag -> release for free
    if (tid == 0)
      __hip_atomic_store(&flags[(((size_t)g * 512 + t) << 6) + s], 1u, __ATOMIC_RELAXED,
                         __HIP_MEMORY_SCOPE_AGENT);
  }
}

// ---------------- launch ----------------
extern "C" void kernel_launch(void* const* d_in, const int* in_sizes, int n_in, void* d_out,
                              int out_size, void* d_ws, size_t ws_size, hipStream_t stream) {
  const float* emb = (const float*)d_in[0];   // [64,512,1024]
  const int* slen = (const int*)d_in[1];      // [64]
  const float* Wih = (const float*)d_in[2];   // [4096,1024]
  const float* Whh = (const float*)d_in[3];   // [4096,1024]
  const float* bih = (const float*)d_in[4];   // [4096]
  const float* bhh = (const float*)d_in[5];   // [4096]
  float* out = (float*)d_out;

  char* ws = (char*)d_ws;
  _Float16* xproj = (_Float16*)(ws + 0);          // 268,435,456 B
  _Float16* xf = (_Float16*)(ws + 268435456);     //  67,108,864 B (dead after GEMM)
  _Float16* wihf = (_Float16*)(ws + 335544320);   //   8,388,608 B
  _Float16* whhf = (_Float16*)(ws + 343932928);   //   8,388,608 B
  float* bsum = (float*)(ws + 352321536);         //      16,384 B
  // rec-phase buffers alias the dead xf region:
  _Float16* hbuf = (_Float16*)(ws + 268435456);   //     262,144 B
  unsigned* flags = (unsigned*)(ws + 268697600);  //     524,288 B

  k_f32_to_f16<<<(8388608 + 255) / 256, 256, 0, stream>>>(emb, xf, 8388608);
  k_f32_to_f16<<<(1048576 + 255) / 256, 256, 0, stream>>>(Wih, wihf, 1048576);
  k_f32_to_f16<<<(1048576 + 255) / 256, 256, 0, stream>>>(Whh, whhf, 1048576);
  k_bias_sum<<<16, 256, 0, stream>>>(bih, bhh, bsum);
  k_gemm_xproj<<<8192, 256, 0, stream>>>(xf, wihf, bsum, xproj);
  // flags live in xf's region -> zero them AFTER the GEMM consumed xf
  hipMemsetAsync(flags, 0, 524288, stream);
  k_lstm_rec<<<256, 256, 0, stream>>>(whhf, xproj, slen, hbuf, flags, out);
}